// Round 1
// baseline (645.687 us; speedup 1.0000x reference)
//
#include <hip/hip_runtime.h>
#include <cstdint>
#include <cstddef>

#define T_TOK 4096
#define H_DIM 1024
#define I_DIM 2816
#define E_NUM 9

typedef __bf16 bf16;
typedef bf16 bf16x8 __attribute__((ext_vector_type(8)));
typedef float f32x4 __attribute__((ext_vector_type(4)));

constexpr int BM = 128, BN = 128, BK = 32;
constexpr int PAD = 8, LDK = BK + PAD;   // LDS row stride 40 bf16 = 80B -> 2-way max conflict

// ---------------- router: fp32 logits, softmax top-2, renormalized weights ----------------
__global__ __launch_bounds__(256) void k_router(const float* __restrict__ x,
                                                const float* __restrict__ Wr,
                                                int* __restrict__ ridx,
                                                float* __restrict__ rw,
                                                int* __restrict__ counts) {
  int lane = threadIdx.x & 63;
  int wid  = threadIdx.x >> 6;
  int t = blockIdx.x * 4 + wid;            // 1024 blocks * 4 waves = 4096 tokens
  const float* xr = x + (size_t)t * H_DIM;
  float acc[E_NUM];
#pragma unroll
  for (int e = 0; e < E_NUM; ++e) acc[e] = 0.f;
  for (int h = lane; h < H_DIM; h += 64) {
    float xv = xr[h];
    const float* wr = Wr + h * E_NUM;
#pragma unroll
    for (int e = 0; e < E_NUM; ++e) acc[e] += xv * wr[e];
  }
#pragma unroll
  for (int off = 32; off > 0; off >>= 1) {
#pragma unroll
    for (int e = 0; e < E_NUM; ++e) acc[e] += __shfl_xor(acc[e], off);
  }
  if (lane == 0) {
    int i0 = 0;
#pragma unroll
    for (int e = 1; e < E_NUM; ++e) if (acc[e] > acc[i0]) i0 = e;
    int i1 = (i0 == 0) ? 1 : 0;
#pragma unroll
    for (int e = 0; e < E_NUM; ++e) if (e != i0 && acc[e] > acc[i1]) i1 = e;
    float r  = expf(acc[i1] - acc[i0]);      // <= 1, stable
    float w0 = 1.f / (1.f + r);
    float w1 = r / (1.f + r);
    ridx[2 * t]     = i0;
    ridx[2 * t + 1] = i1;
    rw[2 * t]     = w0;
    rw[2 * t + 1] = w1;
    atomicAdd(&counts[i0], 1);
    atomicAdd(&counts[i1], 1);
  }
}

// ---------------- tiny scan: counts -> offsets, zero cursors ----------------
__global__ void k_scan(const int* __restrict__ counts, int* __restrict__ offsets,
                       int* __restrict__ cursor) {
  if (threadIdx.x == 0) {
    int s = 0;
    for (int e = 0; e < E_NUM; ++e) { offsets[e] = s; s += counts[e]; }
    offsets[E_NUM] = s;   // == 2*T_TOK
  }
  if (threadIdx.x < E_NUM) cursor[threadIdx.x] = 0;
}

// ---------------- scatter pair ids into expert-sorted perm ----------------
__global__ __launch_bounds__(256) void k_scatter(const int* __restrict__ ridx,
                                                 const int* __restrict__ offsets,
                                                 int* __restrict__ cursor,
                                                 int* __restrict__ perm) {
  int t = blockIdx.x * 256 + threadIdx.x;
  if (t >= T_TOK) return;
#pragma unroll
  for (int k = 0; k < 2; ++k) {
    int e = ridx[2 * t + k];
    int pos = atomicAdd(&cursor[e], 1);      // order nondeterministic; values per pair deterministic
    perm[offsets[e] + pos] = 2 * t + k;
  }
}

// ---------------- fused gate+up grouped GEMM, silu-mul epilogue -> hidden bf16 ----------------
__global__ __launch_bounds__(256, 2) void k_gateup(const float* __restrict__ x,
                                                   const float* __restrict__ Wg,
                                                   const float* __restrict__ Wu,
                                                   const int* __restrict__ perm,
                                                   const int* __restrict__ offsets,
                                                   bf16* __restrict__ hidden) {
  int e = blockIdx.z;
  int seg0 = offsets[e];
  int cnt  = offsets[e + 1] - seg0;
  int pt = blockIdx.y;
  if (pt * BM >= cnt) return;
  int n0 = blockIdx.x * BN;

  __shared__ bf16 As[BM][LDK];
  __shared__ bf16 Bg[BN][LDK];
  __shared__ bf16 Bu[BN][LDK];

  int tid = threadIdx.x;
  int lane = tid & 63;
  int wid  = tid >> 6;
  int wm = wid >> 1, wn = wid & 1;           // 2x2 waves, 64x64 each
  int l15 = lane & 15, l16 = lane >> 4;

  int srow = tid & 127;                      // staging row (A: pair row, B: i column)
  int skh  = tid >> 7;                       // k half (16 elems)

  int p = pt * BM + srow;
  const float* asrc = nullptr;
  if (p < cnt) {
    int tok = perm[seg0 + p] >> 1;
    asrc = x + (size_t)tok * H_DIM;
  }
  const float* gsrc = Wg + (size_t)e * H_DIM * I_DIM + (n0 + srow);
  const float* usrc = Wu + (size_t)e * H_DIM * I_DIM + (n0 + srow);

  f32x4 accg[4][4], accu[4][4];
#pragma unroll
  for (int m = 0; m < 4; ++m)
#pragma unroll
    for (int n = 0; n < 4; ++n) {
      accg[m][n] = (f32x4){0.f, 0.f, 0.f, 0.f};
      accu[m][n] = (f32x4){0.f, 0.f, 0.f, 0.f};
    }

  for (int k0 = 0; k0 < H_DIM; k0 += BK) {
    // ---- stage A (gathered token rows, fp32 -> bf16) ----
    {
      bf16x8 v0, v1;
      if (asrc) {
        const float* s = asrc + k0 + skh * 16;
        float4 f0 = *reinterpret_cast<const float4*>(s);
        float4 f1 = *reinterpret_cast<const float4*>(s + 4);
        float4 f2 = *reinterpret_cast<const float4*>(s + 8);
        float4 f3 = *reinterpret_cast<const float4*>(s + 12);
        v0[0]=(bf16)f0.x; v0[1]=(bf16)f0.y; v0[2]=(bf16)f0.z; v0[3]=(bf16)f0.w;
        v0[4]=(bf16)f1.x; v0[5]=(bf16)f1.y; v0[6]=(bf16)f1.z; v0[7]=(bf16)f1.w;
        v1[0]=(bf16)f2.x; v1[1]=(bf16)f2.y; v1[2]=(bf16)f2.z; v1[3]=(bf16)f2.w;
        v1[4]=(bf16)f3.x; v1[5]=(bf16)f3.y; v1[6]=(bf16)f3.z; v1[7]=(bf16)f3.w;
      } else {
#pragma unroll
        for (int j = 0; j < 8; ++j) { v0[j] = (bf16)0.f; v1[j] = (bf16)0.f; }
      }
      *reinterpret_cast<bf16x8*>(&As[srow][skh * 16])     = v0;
      *reinterpret_cast<bf16x8*>(&As[srow][skh * 16 + 8]) = v1;
    }
    // ---- stage Bg/Bu transposed: LDS[n][k], column-strip loads (coalesced across lanes) ----
    {
      bf16x8 g0, g1, u0, u1;
#pragma unroll
      for (int kk = 0; kk < 8; ++kk) {
        size_t ko = (size_t)(k0 + skh * 16 + kk) * I_DIM;
        g0[kk] = (bf16)gsrc[ko];
        u0[kk] = (bf16)usrc[ko];
      }
#pragma unroll
      for (int kk = 0; kk < 8; ++kk) {
        size_t ko = (size_t)(k0 + skh * 16 + 8 + kk) * I_DIM;
        g1[kk] = (bf16)gsrc[ko];
        u1[kk] = (bf16)usrc[ko];
      }
      *reinterpret_cast<bf16x8*>(&Bg[srow][skh * 16])     = g0;
      *reinterpret_cast<bf16x8*>(&Bg[srow][skh * 16 + 8]) = g1;
      *reinterpret_cast<bf16x8*>(&Bu[srow][skh * 16])     = u0;
      *reinterpret_cast<bf16x8*>(&Bu[srow][skh * 16 + 8]) = u1;
    }
    __syncthreads();

    bf16x8 af[4], bg[4], bu[4];
#pragma unroll
    for (int m = 0; m < 4; ++m)
      af[m] = *reinterpret_cast<const bf16x8*>(&As[wm * 64 + m * 16 + l15][l16 * 8]);
#pragma unroll
    for (int n = 0; n < 4; ++n) {
      bg[n] = *reinterpret_cast<const bf16x8*>(&Bg[wn * 64 + n * 16 + l15][l16 * 8]);
      bu[n] = *reinterpret_cast<const bf16x8*>(&Bu[wn * 64 + n * 16 + l15][l16 * 8]);
    }
#pragma unroll
    for (int m = 0; m < 4; ++m)
#pragma unroll
      for (int n = 0; n < 4; ++n) {
        accg[m][n] = __builtin_amdgcn_mfma_f32_16x16x32_bf16(af[m], bg[n], accg[m][n], 0, 0, 0);
        accu[m][n] = __builtin_amdgcn_mfma_f32_16x16x32_bf16(af[m], bu[n], accu[m][n], 0, 0, 0);
      }
    __syncthreads();
  }

  // ---- epilogue: hidden = silu(g) * u, bf16 ----
#pragma unroll
  for (int m = 0; m < 4; ++m) {
#pragma unroll
    for (int r = 0; r < 4; ++r) {
      int p_glob = pt * BM + wm * 64 + m * 16 + l16 * 4 + r;
      if (p_glob < cnt) {
        bf16* hrow = hidden + (size_t)(seg0 + p_glob) * I_DIM;
#pragma unroll
        for (int n = 0; n < 4; ++n) {
          int col = n0 + wn * 64 + n * 16 + l15;
          float g = accg[m][n][r];
          float u = accu[m][n][r];
          float h = g / (1.f + __expf(-g)) * u;
          hrow[col] = (bf16)h;
        }
      }
    }
  }
}

// ---------------- down grouped GEMM: pair_out[pair] = hidden_row @ Wd[e] ----------------
__global__ __launch_bounds__(256, 2) void k_down(const bf16* __restrict__ hidden,
                                                 const float* __restrict__ Wd,
                                                 const int* __restrict__ perm,
                                                 const int* __restrict__ offsets,
                                                 float* __restrict__ pair_out) {
  int e = blockIdx.z;
  int seg0 = offsets[e];
  int cnt  = offsets[e + 1] - seg0;
  int pt = blockIdx.y;
  if (pt * BM >= cnt) return;
  int n0 = blockIdx.x * BN;                  // h tile

  __shared__ bf16 As[BM][LDK];
  __shared__ bf16 Bs[BN][LDK];

  int tid = threadIdx.x;
  int lane = tid & 63;
  int wid  = tid >> 6;
  int wm = wid >> 1, wn = wid & 1;
  int l15 = lane & 15, l16 = lane >> 4;

  int srow = tid & 127;
  int skh  = tid >> 7;

  int p = pt * BM + srow;
  const bf16* asrc = nullptr;
  if (p < cnt) asrc = hidden + (size_t)(seg0 + p) * I_DIM;
  const float* bsrc = Wd + (size_t)e * I_DIM * H_DIM + (n0 + srow);

  f32x4 acc[4][4];
#pragma unroll
  for (int m = 0; m < 4; ++m)
#pragma unroll
    for (int n = 0; n < 4; ++n) acc[m][n] = (f32x4){0.f, 0.f, 0.f, 0.f};

  for (int k0 = 0; k0 < I_DIM; k0 += BK) {
    {
      bf16x8 v0, v1;
      if (asrc) {
        v0 = *reinterpret_cast<const bf16x8*>(asrc + k0 + skh * 16);
        v1 = *reinterpret_cast<const bf16x8*>(asrc + k0 + skh * 16 + 8);
      } else {
#pragma unroll
        for (int j = 0; j < 8; ++j) { v0[j] = (bf16)0.f; v1[j] = (bf16)0.f; }
      }
      *reinterpret_cast<bf16x8*>(&As[srow][skh * 16])     = v0;
      *reinterpret_cast<bf16x8*>(&As[srow][skh * 16 + 8]) = v1;
    }
    {
      bf16x8 b0, b1;
#pragma unroll
      for (int kk = 0; kk < 8; ++kk)
        b0[kk] = (bf16)bsrc[(size_t)(k0 + skh * 16 + kk) * H_DIM];
#pragma unroll
      for (int kk = 0; kk < 8; ++kk)
        b1[kk] = (bf16)bsrc[(size_t)(k0 + skh * 16 + 8 + kk) * H_DIM];
      *reinterpret_cast<bf16x8*>(&Bs[srow][skh * 16])     = b0;
      *reinterpret_cast<bf16x8*>(&Bs[srow][skh * 16 + 8]) = b1;
    }
    __syncthreads();

    bf16x8 af[4], bf[4];
#pragma unroll
    for (int m = 0; m < 4; ++m)
      af[m] = *reinterpret_cast<const bf16x8*>(&As[wm * 64 + m * 16 + l15][l16 * 8]);
#pragma unroll
    for (int n = 0; n < 4; ++n)
      bf[n] = *reinterpret_cast<const bf16x8*>(&Bs[wn * 64 + n * 16 + l15][l16 * 8]);
#pragma unroll
    for (int m = 0; m < 4; ++m)
#pragma unroll
      for (int n = 0; n < 4; ++n)
        acc[m][n] = __builtin_amdgcn_mfma_f32_16x16x32_bf16(af[m], bf[n], acc[m][n], 0, 0, 0);
    __syncthreads();
  }

#pragma unroll
  for (int m = 0; m < 4; ++m) {
#pragma unroll
    for (int r = 0; r < 4; ++r) {
      int p_glob = pt * BM + wm * 64 + m * 16 + l16 * 4 + r;
      if (p_glob < cnt) {
        int pair = perm[seg0 + p_glob];
        float* orow = pair_out + (size_t)pair * H_DIM;
#pragma unroll
        for (int n = 0; n < 4; ++n) {
          int col = n0 + wn * 64 + n * 16 + l15;
          orow[col] = acc[m][n][r];
        }
      }
    }
  }
}

// ---------------- combine: out[t] = w0*pair_out[2t] + w1*pair_out[2t+1] ----------------
__global__ __launch_bounds__(256) void k_combine(const float* __restrict__ pair_out,
                                                 const float* __restrict__ rw,
                                                 float* __restrict__ out) {
  int t = blockIdx.x;
  int c = threadIdx.x;                      // 256 threads * 4 floats = 1024
  float w0 = rw[2 * t];
  float w1 = rw[2 * t + 1];
  float4 a = *reinterpret_cast<const float4*>(pair_out + ((size_t)(2 * t)) * H_DIM + c * 4);
  float4 b = *reinterpret_cast<const float4*>(pair_out + ((size_t)(2 * t + 1)) * H_DIM + c * 4);
  float4 o;
  o.x = w0 * a.x + w1 * b.x;
  o.y = w0 * a.y + w1 * b.y;
  o.z = w0 * a.z + w1 * b.z;
  o.w = w0 * a.w + w1 * b.w;
  *reinterpret_cast<float4*>(out + (size_t)t * H_DIM + c * 4) = o;
}

extern "C" void kernel_launch(void* const* d_in, const int* in_sizes, int n_in,
                              void* d_out, int out_size, void* d_ws, size_t ws_size,
                              hipStream_t stream) {
  const float* x  = (const float*)d_in[0];
  const float* Wr = (const float*)d_in[1];
  const float* Wg = (const float*)d_in[2];
  const float* Wu = (const float*)d_in[3];
  const float* Wd = (const float*)d_in[4];
  float* out = (float*)d_out;

  char* ws = (char*)d_ws;
  int*   counts   = (int*)(ws + 0);                 // 16 ints
  int*   cursor   = (int*)(ws + 64);                // 16 ints
  int*   offsets  = (int*)(ws + 128);               // 10 ints
  int*   ridx     = (int*)(ws + 512);               // 8192 ints
  float* rw       = (float*)(ws + 512 + 32768);     // 8192 floats
  int*   perm     = (int*)(ws + 512 + 65536);       // 8192 ints
  bf16*  hidden   = (bf16*)(ws + (size_t)(1 << 20));        // 8192*2816 bf16 = 46.1 MB
  float* pair_out = (float*)(ws + ((size_t)48 << 20));      // 8192*1024 f32 = 32 MB

  hipMemsetAsync(counts, 0, 64, stream);
  k_router<<<dim3(T_TOK / 4), dim3(256), 0, stream>>>(x, Wr, ridx, rw, counts);
  k_scan<<<dim3(1), dim3(64), 0, stream>>>(counts, offsets, cursor);
  k_scatter<<<dim3((T_TOK + 255) / 256), dim3(256), 0, stream>>>(ridx, offsets, cursor, perm);
  k_gateup<<<dim3(I_DIM / BN, (T_TOK + BM - 1) / BM, E_NUM), dim3(256), 0, stream>>>(
      x, Wg, Wu, perm, offsets, hidden);
  k_down<<<dim3(H_DIM / BN, (T_TOK + BM - 1) / BM, E_NUM), dim3(256), 0, stream>>>(
      hidden, Wd, perm, offsets, pair_out);
  k_combine<<<dim3(T_TOK), dim3(256), 0, stream>>>(pair_out, rw, out);
}

// Round 2
// 613.110 us; speedup vs baseline: 1.0531x; 1.0531x over previous
//
#include <hip/hip_runtime.h>
#include <cstdint>
#include <cstddef>

#define T_TOK 4096
#define H_DIM 1024
#define I_DIM 2816
#define E_NUM 9
#define MAXTILE 76

typedef __bf16 bf16;
typedef bf16 bf16x4 __attribute__((ext_vector_type(4)));
typedef bf16 bf16x8 __attribute__((ext_vector_type(8)));
typedef float f32x4 __attribute__((ext_vector_type(4)));

constexpr int BM = 128, BN = 128, BK = 32;
constexpr int PAD = 8, LDK = BK + PAD;   // 40 bf16 = 80B row stride -> 2-way max (free)

// ---------------- x: fp32 -> bf16 ----------------
__global__ __launch_bounds__(256) void k_xcast(const float* __restrict__ x, bf16* __restrict__ xb) {
  size_t i = ((size_t)blockIdx.x * 256 + threadIdx.x) * 8;
  float4 a = *reinterpret_cast<const float4*>(x + i);
  float4 b = *reinterpret_cast<const float4*>(x + i + 4);
  bf16x8 v;
  v[0]=(bf16)a.x; v[1]=(bf16)a.y; v[2]=(bf16)a.z; v[3]=(bf16)a.w;
  v[4]=(bf16)b.x; v[5]=(bf16)b.y; v[6]=(bf16)b.z; v[7]=(bf16)b.w;
  *reinterpret_cast<bf16x8*>(xb + i) = v;
}

// ------- per-expert transpose+convert: in [R][C] fp32 -> out [C][R] bf16 -------
__global__ __launch_bounds__(256) void k_transpose(const float* __restrict__ in,
                                                   bf16* __restrict__ out, int R, int C) {
  const float* src = in + (size_t)blockIdx.z * R * C;
  bf16* dst = out + (size_t)blockIdx.z * R * C;
  __shared__ bf16 tile[64][72];
  int r0 = blockIdx.y * 64, c0 = blockIdx.x * 64;
  int t = threadIdx.x;
  int tr = t >> 4, tc = (t & 15) * 4;
#pragma unroll
  for (int it = 0; it < 4; ++it) {
    int r = tr + it * 16;
    float4 v = *reinterpret_cast<const float4*>(src + (size_t)(r0 + r) * C + c0 + tc);
    bf16x4 w; w[0]=(bf16)v.x; w[1]=(bf16)v.y; w[2]=(bf16)v.z; w[3]=(bf16)v.w;
    *reinterpret_cast<bf16x4*>(&tile[r][tc]) = w;
  }
  __syncthreads();
#pragma unroll
  for (int it = 0; it < 4; ++it) {
    int oc = tr + it * 16;
    bf16x4 w;
    w[0] = tile[tc + 0][oc]; w[1] = tile[tc + 1][oc];
    w[2] = tile[tc + 2][oc]; w[3] = tile[tc + 3][oc];
    *reinterpret_cast<bf16x4*>(dst + (size_t)(c0 + oc) * R + r0 + tc) = w;
  }
}

// ---------------- router: fp32 logits, softmax top-2, renormalized ----------------
__global__ __launch_bounds__(256) void k_router(const float* __restrict__ x,
                                                const float* __restrict__ Wr,
                                                int* __restrict__ ridx,
                                                float* __restrict__ rw,
                                                int* __restrict__ counts) {
  int lane = threadIdx.x & 63;
  int wid  = threadIdx.x >> 6;
  int t = blockIdx.x * 4 + wid;
  const float* xr = x + (size_t)t * H_DIM;
  float acc[E_NUM];
#pragma unroll
  for (int e = 0; e < E_NUM; ++e) acc[e] = 0.f;
  for (int h = lane; h < H_DIM; h += 64) {
    float xv = xr[h];
    const float* wr = Wr + h * E_NUM;
#pragma unroll
    for (int e = 0; e < E_NUM; ++e) acc[e] += xv * wr[e];
  }
#pragma unroll
  for (int off = 32; off > 0; off >>= 1) {
#pragma unroll
    for (int e = 0; e < E_NUM; ++e) acc[e] += __shfl_xor(acc[e], off);
  }
  if (lane == 0) {
    int i0 = 0;
#pragma unroll
    for (int e = 1; e < E_NUM; ++e) if (acc[e] > acc[i0]) i0 = e;
    int i1 = (i0 == 0) ? 1 : 0;
#pragma unroll
    for (int e = 0; e < E_NUM; ++e) if (e != i0 && acc[e] > acc[i1]) i1 = e;
    float r  = expf(acc[i1] - acc[i0]);
    float w0 = 1.f / (1.f + r);
    float w1 = r / (1.f + r);
    ridx[2 * t]     = i0;
    ridx[2 * t + 1] = i1;
    rw[2 * t]     = w0;
    rw[2 * t + 1] = w1;
    atomicAdd(&counts[i0], 1);
    atomicAdd(&counts[i1], 1);
  }
}

// ------- scan: counts -> offsets, build compact tile list, zero cursors -------
__global__ void k_scan(const int* __restrict__ counts, int* __restrict__ offsets,
                       int* __restrict__ cursor, int* __restrict__ tiles,
                       int* __restrict__ n_tiles) {
  if (threadIdx.x == 0) {
    int s = 0, nt = 0;
    for (int e = 0; e < E_NUM; ++e) {
      offsets[e] = s;
      int c = counts[e];
      for (int pt = 0; pt * BM < c && nt < MAXTILE; ++pt) tiles[nt++] = (e << 16) | pt;
      s += c;
    }
    offsets[E_NUM] = s;
    *n_tiles = nt;
  }
  if (threadIdx.x < E_NUM) cursor[threadIdx.x] = 0;
}

// ---------------- scatter pair ids into expert-sorted perm ----------------
__global__ __launch_bounds__(256) void k_scatter(const int* __restrict__ ridx,
                                                 const int* __restrict__ offsets,
                                                 int* __restrict__ cursor,
                                                 int* __restrict__ perm) {
  int t = blockIdx.x * 256 + threadIdx.x;
  if (t >= T_TOK) return;
#pragma unroll
  for (int k = 0; k < 2; ++k) {
    int e = ridx[2 * t + k];
    int pos = atomicAdd(&cursor[e], 1);
    perm[offsets[e] + pos] = 2 * t + k;
  }
}

// ------- fused gate+up grouped GEMM (bf16 operands), silu-mul -> hidden bf16 -------
__global__ __launch_bounds__(256, 2) void k_gateup(const bf16* __restrict__ xb,
                                                   const bf16* __restrict__ WgT,
                                                   const bf16* __restrict__ WuT,
                                                   const int* __restrict__ perm,
                                                   const int* __restrict__ offsets,
                                                   const int* __restrict__ tiles,
                                                   const int* __restrict__ n_tiles,
                                                   bf16* __restrict__ hidden) {
  if ((int)blockIdx.y >= *n_tiles) return;
  int tv = tiles[blockIdx.y];
  int e = tv >> 16, pt = tv & 0xffff;
  int seg0 = offsets[e], cnt = offsets[e + 1] - seg0;
  int n0 = blockIdx.x * BN;

  __shared__ bf16 As[BM][LDK];
  __shared__ bf16 Bg[BN][LDK];
  __shared__ bf16 Bu[BN][LDK];

  int tid = threadIdx.x, lane = tid & 63, wid = tid >> 6;
  int wm = wid >> 1, wn = wid & 1, l15 = lane & 15, l16 = lane >> 4;
  int srow = tid & 127, skh = tid >> 7;   // each thread stages 16 contiguous k of one row

  int p = pt * BM + srow;
  const bf16* asrc = nullptr;
  if (p < cnt) asrc = xb + (size_t)(perm[seg0 + p] >> 1) * H_DIM;
  const bf16* gsrc = WgT + ((size_t)e * I_DIM + n0 + srow) * H_DIM;
  const bf16* usrc = WuT + ((size_t)e * I_DIM + n0 + srow) * H_DIM;

  f32x4 accg[4][4], accu[4][4];
#pragma unroll
  for (int m = 0; m < 4; ++m)
#pragma unroll
    for (int n = 0; n < 4; ++n) {
      accg[m][n] = (f32x4){0.f, 0.f, 0.f, 0.f};
      accu[m][n] = (f32x4){0.f, 0.f, 0.f, 0.f};
    }

  for (int k0 = 0; k0 < H_DIM; k0 += BK) {
    int kk = k0 + skh * 16;
    uint4 a0, a1;
    if (asrc) {
      a0 = *reinterpret_cast<const uint4*>(asrc + kk);
      a1 = *reinterpret_cast<const uint4*>(asrc + kk + 8);
    } else {
      a0 = (uint4){0, 0, 0, 0}; a1 = (uint4){0, 0, 0, 0};
    }
    uint4 g0 = *reinterpret_cast<const uint4*>(gsrc + kk);
    uint4 g1 = *reinterpret_cast<const uint4*>(gsrc + kk + 8);
    uint4 u0 = *reinterpret_cast<const uint4*>(usrc + kk);
    uint4 u1 = *reinterpret_cast<const uint4*>(usrc + kk + 8);
    *reinterpret_cast<uint4*>(&As[srow][skh * 16])     = a0;
    *reinterpret_cast<uint4*>(&As[srow][skh * 16 + 8]) = a1;
    *reinterpret_cast<uint4*>(&Bg[srow][skh * 16])     = g0;
    *reinterpret_cast<uint4*>(&Bg[srow][skh * 16 + 8]) = g1;
    *reinterpret_cast<uint4*>(&Bu[srow][skh * 16])     = u0;
    *reinterpret_cast<uint4*>(&Bu[srow][skh * 16 + 8]) = u1;
    __syncthreads();

    bf16x8 af[4], bg[4], bu[4];
#pragma unroll
    for (int m = 0; m < 4; ++m)
      af[m] = *reinterpret_cast<const bf16x8*>(&As[wm * 64 + m * 16 + l15][l16 * 8]);
#pragma unroll
    for (int n = 0; n < 4; ++n) {
      bg[n] = *reinterpret_cast<const bf16x8*>(&Bg[wn * 64 + n * 16 + l15][l16 * 8]);
      bu[n] = *reinterpret_cast<const bf16x8*>(&Bu[wn * 64 + n * 16 + l15][l16 * 8]);
    }
#pragma unroll
    for (int m = 0; m < 4; ++m)
#pragma unroll
      for (int n = 0; n < 4; ++n) {
        accg[m][n] = __builtin_amdgcn_mfma_f32_16x16x32_bf16(af[m], bg[n], accg[m][n], 0, 0, 0);
        accu[m][n] = __builtin_amdgcn_mfma_f32_16x16x32_bf16(af[m], bu[n], accu[m][n], 0, 0, 0);
      }
    __syncthreads();
  }

#pragma unroll
  for (int m = 0; m < 4; ++m) {
#pragma unroll
    for (int r = 0; r < 4; ++r) {
      int p_glob = pt * BM + wm * 64 + m * 16 + l16 * 4 + r;
      if (p_glob < cnt) {
        bf16* hrow = hidden + (size_t)(seg0 + p_glob) * I_DIM;
#pragma unroll
        for (int n = 0; n < 4; ++n) {
          int col = n0 + wn * 64 + n * 16 + l15;
          float g = accg[m][n][r];
          float u = accu[m][n][r];
          float h = g / (1.f + __expf(-g)) * u;
          hrow[col] = (bf16)h;
        }
      }
    }
  }
}

// ------- down grouped GEMM (bf16 operands): pair_out[pair] = hidden @ WdT[e] -------
__global__ __launch_bounds__(256, 2) void k_down(const bf16* __restrict__ hidden,
                                                 const bf16* __restrict__ WdT,
                                                 const int* __restrict__ perm,
                                                 const int* __restrict__ offsets,
                                                 const int* __restrict__ tiles,
                                                 const int* __restrict__ n_tiles,
                                                 float* __restrict__ pair_out) {
  if ((int)blockIdx.y >= *n_tiles) return;
  int tv = tiles[blockIdx.y];
  int e = tv >> 16, pt = tv & 0xffff;
  int seg0 = offsets[e], cnt = offsets[e + 1] - seg0;
  int n0 = blockIdx.x * BN;

  __shared__ bf16 As[BM][LDK];
  __shared__ bf16 Bs[BN][LDK];

  int tid = threadIdx.x, lane = tid & 63, wid = tid >> 6;
  int wm = wid >> 1, wn = wid & 1, l15 = lane & 15, l16 = lane >> 4;
  int srow = tid & 127, skh = tid >> 7;

  int p = pt * BM + srow;
  const bf16* asrc = nullptr;
  if (p < cnt) asrc = hidden + (size_t)(seg0 + p) * I_DIM;
  const bf16* bsrc = WdT + ((size_t)e * H_DIM + n0 + srow) * I_DIM;

  f32x4 acc[4][4];
#pragma unroll
  for (int m = 0; m < 4; ++m)
#pragma unroll
    for (int n = 0; n < 4; ++n) acc[m][n] = (f32x4){0.f, 0.f, 0.f, 0.f};

  for (int k0 = 0; k0 < I_DIM; k0 += BK) {
    int kk = k0 + skh * 16;
    uint4 a0, a1;
    if (asrc) {
      a0 = *reinterpret_cast<const uint4*>(asrc + kk);
      a1 = *reinterpret_cast<const uint4*>(asrc + kk + 8);
    } else {
      a0 = (uint4){0, 0, 0, 0}; a1 = (uint4){0, 0, 0, 0};
    }
    uint4 b0 = *reinterpret_cast<const uint4*>(bsrc + kk);
    uint4 b1 = *reinterpret_cast<const uint4*>(bsrc + kk + 8);
    *reinterpret_cast<uint4*>(&As[srow][skh * 16])     = a0;
    *reinterpret_cast<uint4*>(&As[srow][skh * 16 + 8]) = a1;
    *reinterpret_cast<uint4*>(&Bs[srow][skh * 16])     = b0;
    *reinterpret_cast<uint4*>(&Bs[srow][skh * 16 + 8]) = b1;
    __syncthreads();

    bf16x8 af[4], bfr[4];
#pragma unroll
    for (int m = 0; m < 4; ++m)
      af[m] = *reinterpret_cast<const bf16x8*>(&As[wm * 64 + m * 16 + l15][l16 * 8]);
#pragma unroll
    for (int n = 0; n < 4; ++n)
      bfr[n] = *reinterpret_cast<const bf16x8*>(&Bs[wn * 64 + n * 16 + l15][l16 * 8]);
#pragma unroll
    for (int m = 0; m < 4; ++m)
#pragma unroll
      for (int n = 0; n < 4; ++n)
        acc[m][n] = __builtin_amdgcn_mfma_f32_16x16x32_bf16(af[m], bfr[n], acc[m][n], 0, 0, 0);
    __syncthreads();
  }

#pragma unroll
  for (int m = 0; m < 4; ++m) {
#pragma unroll
    for (int r = 0; r < 4; ++r) {
      int p_glob = pt * BM + wm * 64 + m * 16 + l16 * 4 + r;
      if (p_glob < cnt) {
        int pair = perm[seg0 + p_glob];
        float* orow = pair_out + (size_t)pair * H_DIM;
#pragma unroll
        for (int n = 0; n < 4; ++n) {
          int col = n0 + wn * 64 + n * 16 + l15;
          orow[col] = acc[m][n][r];
        }
      }
    }
  }
}

// ---------------- combine: out[t] = w0*pair_out[2t] + w1*pair_out[2t+1] ----------------
__global__ __launch_bounds__(256) void k_combine(const float* __restrict__ pair_out,
                                                 const float* __restrict__ rw,
                                                 float* __restrict__ out) {
  int t = blockIdx.x;
  int c = threadIdx.x;
  float w0 = rw[2 * t];
  float w1 = rw[2 * t + 1];
  float4 a = *reinterpret_cast<const float4*>(pair_out + ((size_t)(2 * t)) * H_DIM + c * 4);
  float4 b = *reinterpret_cast<const float4*>(pair_out + ((size_t)(2 * t + 1)) * H_DIM + c * 4);
  float4 o;
  o.x = w0 * a.x + w1 * b.x;
  o.y = w0 * a.y + w1 * b.y;
  o.z = w0 * a.z + w1 * b.z;
  o.w = w0 * a.w + w1 * b.w;
  *reinterpret_cast<float4*>(out + (size_t)t * H_DIM + c * 4) = o;
}

extern "C" void kernel_launch(void* const* d_in, const int* in_sizes, int n_in,
                              void* d_out, int out_size, void* d_ws, size_t ws_size,
                              hipStream_t stream) {
  const float* x  = (const float*)d_in[0];
  const float* Wr = (const float*)d_in[1];
  const float* Wg = (const float*)d_in[2];
  const float* Wu = (const float*)d_in[3];
  const float* Wd = (const float*)d_in[4];
  float* out = (float*)d_out;

  char* ws = (char*)d_ws;
  int*   counts  = (int*)(ws);
  int*   cursor  = (int*)(ws + 256);
  int*   offsets = (int*)(ws + 512);
  int*   n_tiles = (int*)(ws + 768);
  int*   tiles   = (int*)(ws + 1024);
  int*   ridx    = (int*)(ws + 64 * 1024);
  float* rw      = (float*)(ws + 128 * 1024);
  int*   perm    = (int*)(ws + 192 * 1024);
  bf16*  xb      = (bf16*)(ws + (1ull << 20));       //  8.4 MB
  bf16*  WgT     = (bf16*)(ws + (16ull << 20));      // 49.5 MiB each
  bf16*  WuT     = (bf16*)(ws + (66ull << 20));
  bf16*  WdT     = (bf16*)(ws + (116ull << 20));
  bf16*  hidden  = (bf16*)(ws + (166ull << 20));     // 44 MiB
  float* pair_out = (float*)(ws + (212ull << 20));   // 32 MiB -> total ~244 MiB

  hipMemsetAsync(counts, 0, 64, stream);
  k_xcast<<<dim3(T_TOK * H_DIM / 2048), dim3(256), 0, stream>>>(x, xb);
  k_transpose<<<dim3(I_DIM / 64, H_DIM / 64, E_NUM), dim3(256), 0, stream>>>(Wg, WgT, H_DIM, I_DIM);
  k_transpose<<<dim3(I_DIM / 64, H_DIM / 64, E_NUM), dim3(256), 0, stream>>>(Wu, WuT, H_DIM, I_DIM);
  k_transpose<<<dim3(H_DIM / 64, I_DIM / 64, E_NUM), dim3(256), 0, stream>>>(Wd, WdT, I_DIM, H_DIM);
  k_router<<<dim3(T_TOK / 4), dim3(256), 0, stream>>>(x, Wr, ridx, rw, counts);
  k_scan<<<dim3(1), dim3(64), 0, stream>>>(counts, offsets, cursor, tiles, n_tiles);
  k_scatter<<<dim3((T_TOK + 255) / 256), dim3(256), 0, stream>>>(ridx, offsets, cursor, perm);
  k_gateup<<<dim3(I_DIM / BN, MAXTILE), dim3(256), 0, stream>>>(
      xb, WgT, WuT, perm, offsets, tiles, n_tiles, hidden);
  k_down<<<dim3(H_DIM / BN, MAXTILE), dim3(256), 0, stream>>>(
      hidden, WdT, perm, offsets, tiles, n_tiles, pair_out);
  k_combine<<<dim3(T_TOK), dim3(256), 0, stream>>>(pair_out, rw, out);
}

// Round 3
// 486.433 us; speedup vs baseline: 1.3274x; 1.2604x over previous
//
#include <hip/hip_runtime.h>
#include <cstdint>
#include <cstddef>

#define T_TOK 4096
#define H_DIM 1024
#define I_DIM 2816
#define E_NUM 9
#define MAXTILE 76

typedef __bf16 bf16;
typedef bf16 bf16x4 __attribute__((ext_vector_type(4)));
typedef bf16 bf16x8 __attribute__((ext_vector_type(8)));
typedef float f32x4 __attribute__((ext_vector_type(4)));

constexpr int BM = 128, BN = 128, BK = 32;

// async global->LDS, 16B per lane; LDS dest must be linear (wave-uniform base + lane*16)
#define GL16(gp, lp)                                                                   \
  __builtin_amdgcn_global_load_lds((const __attribute__((address_space(1))) void*)(gp), \
                                   (__attribute__((address_space(3))) void*)(lp), 16, 0, 0)

// ---------------- x: fp32 -> bf16 ----------------
__global__ __launch_bounds__(256) void k_xcast(const float* __restrict__ x, bf16* __restrict__ xb) {
  size_t i = ((size_t)blockIdx.x * 256 + threadIdx.x) * 8;
  float4 a = *reinterpret_cast<const float4*>(x + i);
  float4 b = *reinterpret_cast<const float4*>(x + i + 4);
  bf16x8 v;
  v[0]=(bf16)a.x; v[1]=(bf16)a.y; v[2]=(bf16)a.z; v[3]=(bf16)a.w;
  v[4]=(bf16)b.x; v[5]=(bf16)b.y; v[6]=(bf16)b.z; v[7]=(bf16)b.w;
  *reinterpret_cast<bf16x8*>(xb + i) = v;
}

// ------- per-expert transpose+convert: in [R][C] fp32 -> out [C][R] bf16 -------
__global__ __launch_bounds__(256) void k_transpose(const float* __restrict__ in,
                                                   bf16* __restrict__ out, int R, int C) {
  const float* src = in + (size_t)blockIdx.z * R * C;
  bf16* dst = out + (size_t)blockIdx.z * R * C;
  __shared__ bf16 tile[64][72];
  int r0 = blockIdx.y * 64, c0 = blockIdx.x * 64;
  int t = threadIdx.x;
  int tr = t >> 4, tc = (t & 15) * 4;
#pragma unroll
  for (int it = 0; it < 4; ++it) {
    int r = tr + it * 16;
    float4 v = *reinterpret_cast<const float4*>(src + (size_t)(r0 + r) * C + c0 + tc);
    bf16x4 w; w[0]=(bf16)v.x; w[1]=(bf16)v.y; w[2]=(bf16)v.z; w[3]=(bf16)v.w;
    *reinterpret_cast<bf16x4*>(&tile[r][tc]) = w;
  }
  __syncthreads();
#pragma unroll
  for (int it = 0; it < 4; ++it) {
    int oc = tr + it * 16;
    bf16x4 w;
    w[0] = tile[tc + 0][oc]; w[1] = tile[tc + 1][oc];
    w[2] = tile[tc + 2][oc]; w[3] = tile[tc + 3][oc];
    *reinterpret_cast<bf16x4*>(dst + (size_t)(c0 + oc) * R + r0 + tc) = w;
  }
}

// ---------------- router: fp32 logits, softmax top-2, renormalized ----------------
__global__ __launch_bounds__(256) void k_router(const float* __restrict__ x,
                                                const float* __restrict__ Wr,
                                                int* __restrict__ ridx,
                                                float* __restrict__ rw,
                                                int* __restrict__ counts) {
  int lane = threadIdx.x & 63;
  int wid  = threadIdx.x >> 6;
  int t = blockIdx.x * 4 + wid;
  const float* xr = x + (size_t)t * H_DIM;
  float acc[E_NUM];
#pragma unroll
  for (int e = 0; e < E_NUM; ++e) acc[e] = 0.f;
  for (int h = lane; h < H_DIM; h += 64) {
    float xv = xr[h];
    const float* wr = Wr + h * E_NUM;
#pragma unroll
    for (int e = 0; e < E_NUM; ++e) acc[e] += xv * wr[e];
  }
#pragma unroll
  for (int off = 32; off > 0; off >>= 1) {
#pragma unroll
    for (int e = 0; e < E_NUM; ++e) acc[e] += __shfl_xor(acc[e], off);
  }
  if (lane == 0) {
    int i0 = 0;
#pragma unroll
    for (int e = 1; e < E_NUM; ++e) if (acc[e] > acc[i0]) i0 = e;
    int i1 = (i0 == 0) ? 1 : 0;
#pragma unroll
    for (int e = 0; e < E_NUM; ++e) if (e != i0 && acc[e] > acc[i1]) i1 = e;
    float r  = expf(acc[i1] - acc[i0]);
    float w0 = 1.f / (1.f + r);
    float w1 = r / (1.f + r);
    ridx[2 * t]     = i0;
    ridx[2 * t + 1] = i1;
    rw[2 * t]     = w0;
    rw[2 * t + 1] = w1;
    atomicAdd(&counts[i0], 1);
    atomicAdd(&counts[i1], 1);
  }
}

// ------- scan: counts -> offsets, compact tile list, zero cursors -------
__global__ void k_scan(const int* __restrict__ counts, int* __restrict__ offsets,
                       int* __restrict__ cursor, int* __restrict__ tiles,
                       int* __restrict__ n_tiles) {
  if (threadIdx.x == 0) {
    int s = 0, nt = 0;
    for (int e = 0; e < E_NUM; ++e) {
      offsets[e] = s;
      int c = counts[e];
      for (int pt = 0; pt * BM < c && nt < MAXTILE; ++pt) tiles[nt++] = (e << 16) | pt;
      s += c;
    }
    offsets[E_NUM] = s;
    *n_tiles = nt;
  }
  if (threadIdx.x < E_NUM) cursor[threadIdx.x] = 0;
}

// ---------------- scatter pair ids into expert-sorted perm ----------------
__global__ __launch_bounds__(256) void k_scatter(const int* __restrict__ ridx,
                                                 const int* __restrict__ offsets,
                                                 int* __restrict__ cursor,
                                                 int* __restrict__ perm) {
  int t = blockIdx.x * 256 + threadIdx.x;
  if (t >= T_TOK) return;
#pragma unroll
  for (int k = 0; k < 2; ++k) {
    int e = ridx[2 * t + k];
    int pos = atomicAdd(&cursor[e], 1);
    perm[offsets[e] + pos] = 2 * t + k;
  }
}

// ------- fused gate+up grouped GEMM: global_load_lds staging, linear LDS -------
__global__ __launch_bounds__(256, 2) void k_gateup(const bf16* __restrict__ xb,
                                                   const bf16* __restrict__ WgT,
                                                   const bf16* __restrict__ WuT,
                                                   const int* __restrict__ perm,
                                                   const int* __restrict__ offsets,
                                                   const int* __restrict__ tiles,
                                                   const int* __restrict__ n_tiles,
                                                   bf16* __restrict__ hidden) {
  if ((int)blockIdx.y >= *n_tiles) return;
  int tv = tiles[blockIdx.y];
  int e = tv >> 16, pt = tv & 0xffff;
  int seg0 = offsets[e], cnt = offsets[e + 1] - seg0;
  int n0 = blockIdx.x * BN;

  __shared__ bf16 As[BM * BK];
  __shared__ bf16 Bg[BN * BK];
  __shared__ bf16 Bu[BN * BK];

  int tid = threadIdx.x, lane = tid & 63, wid = tid >> 6;
  int wm = wid >> 1, wn = wid & 1, l15 = lane & 15, l16 = lane >> 4;

  // staging map: chunk c (=tid, tid+256) -> row c>>2, k-offset (c&3)*8; LDS elem offset c*8
  int srow1 = tid >> 2, srow2 = 64 + (tid >> 2);
  int kc = (tid & 3) * 8;
  int p1 = pt * BM + srow1, p2 = pt * BM + srow2;
  const bf16* a1 = xb + (size_t)(perm[seg0 + (p1 < cnt ? p1 : 0)] >> 1) * H_DIM + kc;
  const bf16* a2 = xb + (size_t)(perm[seg0 + (p2 < cnt ? p2 : 0)] >> 1) * H_DIM + kc;
  const bf16* g1 = WgT + ((size_t)e * I_DIM + n0 + srow1) * H_DIM + kc;
  const bf16* g2 = WgT + ((size_t)e * I_DIM + n0 + srow2) * H_DIM + kc;
  const bf16* u1 = WuT + ((size_t)e * I_DIM + n0 + srow1) * H_DIM + kc;
  const bf16* u2 = WuT + ((size_t)e * I_DIM + n0 + srow2) * H_DIM + kc;
  bf16* lA1 = &As[tid * 8];       bf16* lA2 = &As[2048 + tid * 8];
  bf16* lG1 = &Bg[tid * 8];       bf16* lG2 = &Bg[2048 + tid * 8];
  bf16* lU1 = &Bu[tid * 8];       bf16* lU2 = &Bu[2048 + tid * 8];

  f32x4 accg[4][4], accu[4][4];
#pragma unroll
  for (int m = 0; m < 4; ++m)
#pragma unroll
    for (int n = 0; n < 4; ++n) {
      accg[m][n] = (f32x4){0.f, 0.f, 0.f, 0.f};
      accu[m][n] = (f32x4){0.f, 0.f, 0.f, 0.f};
    }

  for (int k0 = 0; k0 < H_DIM; k0 += BK) {
    GL16(a1 + k0, lA1);  GL16(a2 + k0, lA2);
    GL16(g1 + k0, lG1);  GL16(g2 + k0, lG2);
    GL16(u1 + k0, lU1);  GL16(u2 + k0, lU2);
    __syncthreads();                 // drains vmcnt -> LDS tiles ready

    bf16x8 af[4], bg[4], bu[4];
#pragma unroll
    for (int m = 0; m < 4; ++m)
      af[m] = *reinterpret_cast<const bf16x8*>(&As[(wm * 64 + m * 16 + l15) * BK + l16 * 8]);
#pragma unroll
    for (int n = 0; n < 4; ++n) {
      bg[n] = *reinterpret_cast<const bf16x8*>(&Bg[(wn * 64 + n * 16 + l15) * BK + l16 * 8]);
      bu[n] = *reinterpret_cast<const bf16x8*>(&Bu[(wn * 64 + n * 16 + l15) * BK + l16 * 8]);
    }
#pragma unroll
    for (int m = 0; m < 4; ++m)
#pragma unroll
      for (int n = 0; n < 4; ++n) {
        accg[m][n] = __builtin_amdgcn_mfma_f32_16x16x32_bf16(af[m], bg[n], accg[m][n], 0, 0, 0);
        accu[m][n] = __builtin_amdgcn_mfma_f32_16x16x32_bf16(af[m], bu[n], accu[m][n], 0, 0, 0);
      }
    __syncthreads();
  }

#pragma unroll
  for (int m = 0; m < 4; ++m) {
#pragma unroll
    for (int r = 0; r < 4; ++r) {
      int p_glob = pt * BM + wm * 64 + m * 16 + l16 * 4 + r;
      if (p_glob < cnt) {
        bf16* hrow = hidden + (size_t)(seg0 + p_glob) * I_DIM;
#pragma unroll
        for (int n = 0; n < 4; ++n) {
          int col = n0 + wn * 64 + n * 16 + l15;
          float g = accg[m][n][r];
          float u = accu[m][n][r];
          float h = g / (1.f + __expf(-g)) * u;
          hrow[col] = (bf16)h;
        }
      }
    }
  }
}

// ------- down grouped GEMM: global_load_lds staging, linear LDS -------
__global__ __launch_bounds__(256, 2) void k_down(const bf16* __restrict__ hidden,
                                                 const bf16* __restrict__ WdT,
                                                 const int* __restrict__ perm,
                                                 const int* __restrict__ offsets,
                                                 const int* __restrict__ tiles,
                                                 const int* __restrict__ n_tiles,
                                                 float* __restrict__ pair_out) {
  if ((int)blockIdx.y >= *n_tiles) return;
  int tv = tiles[blockIdx.y];
  int e = tv >> 16, pt = tv & 0xffff;
  int seg0 = offsets[e], cnt = offsets[e + 1] - seg0;
  int n0 = blockIdx.x * BN;

  __shared__ bf16 As[BM * BK];
  __shared__ bf16 Bs[BN * BK];

  int tid = threadIdx.x, lane = tid & 63, wid = tid >> 6;
  int wm = wid >> 1, wn = wid & 1, l15 = lane & 15, l16 = lane >> 4;

  int srow1 = tid >> 2, srow2 = 64 + (tid >> 2);
  int kc = (tid & 3) * 8;
  int p1 = pt * BM + srow1, p2 = pt * BM + srow2;
  const bf16* a1 = hidden + (size_t)(seg0 + (p1 < cnt ? p1 : 0)) * I_DIM + kc;
  const bf16* a2 = hidden + (size_t)(seg0 + (p2 < cnt ? p2 : 0)) * I_DIM + kc;
  const bf16* b1 = WdT + ((size_t)e * H_DIM + n0 + srow1) * I_DIM + kc;
  const bf16* b2 = WdT + ((size_t)e * H_DIM + n0 + srow2) * I_DIM + kc;
  bf16* lA1 = &As[tid * 8];  bf16* lA2 = &As[2048 + tid * 8];
  bf16* lB1 = &Bs[tid * 8];  bf16* lB2 = &Bs[2048 + tid * 8];

  f32x4 acc[4][4];
#pragma unroll
  for (int m = 0; m < 4; ++m)
#pragma unroll
    for (int n = 0; n < 4; ++n) acc[m][n] = (f32x4){0.f, 0.f, 0.f, 0.f};

  for (int k0 = 0; k0 < I_DIM; k0 += BK) {
    GL16(a1 + k0, lA1);  GL16(a2 + k0, lA2);
    GL16(b1 + k0, lB1);  GL16(b2 + k0, lB2);
    __syncthreads();

    bf16x8 af[4], bfr[4];
#pragma unroll
    for (int m = 0; m < 4; ++m)
      af[m] = *reinterpret_cast<const bf16x8*>(&As[(wm * 64 + m * 16 + l15) * BK + l16 * 8]);
#pragma unroll
    for (int n = 0; n < 4; ++n)
      bfr[n] = *reinterpret_cast<const bf16x8*>(&Bs[(wn * 64 + n * 16 + l15) * BK + l16 * 8]);
#pragma unroll
    for (int m = 0; m < 4; ++m)
#pragma unroll
      for (int n = 0; n < 4; ++n)
        acc[m][n] = __builtin_amdgcn_mfma_f32_16x16x32_bf16(af[m], bfr[n], acc[m][n], 0, 0, 0);
    __syncthreads();
  }

#pragma unroll
  for (int m = 0; m < 4; ++m) {
#pragma unroll
    for (int r = 0; r < 4; ++r) {
      int p_glob = pt * BM + wm * 64 + m * 16 + l16 * 4 + r;
      if (p_glob < cnt) {
        int pair = perm[seg0 + p_glob];
        float* orow = pair_out + (size_t)pair * H_DIM;
#pragma unroll
        for (int n = 0; n < 4; ++n) {
          int col = n0 + wn * 64 + n * 16 + l15;
          orow[col] = acc[m][n][r];
        }
      }
    }
  }
}

// ---------------- combine ----------------
__global__ __launch_bounds__(256) void k_combine(const float* __restrict__ pair_out,
                                                 const float* __restrict__ rw,
                                                 float* __restrict__ out) {
  int t = blockIdx.x;
  int c = threadIdx.x;
  float w0 = rw[2 * t];
  float w1 = rw[2 * t + 1];
  float4 a = *reinterpret_cast<const float4*>(pair_out + ((size_t)(2 * t)) * H_DIM + c * 4);
  float4 b = *reinterpret_cast<const float4*>(pair_out + ((size_t)(2 * t + 1)) * H_DIM + c * 4);
  float4 o;
  o.x = w0 * a.x + w1 * b.x;
  o.y = w0 * a.y + w1 * b.y;
  o.z = w0 * a.z + w1 * b.z;
  o.w = w0 * a.w + w1 * b.w;
  *reinterpret_cast<float4*>(out + (size_t)t * H_DIM + c * 4) = o;
}

extern "C" void kernel_launch(void* const* d_in, const int* in_sizes, int n_in,
                              void* d_out, int out_size, void* d_ws, size_t ws_size,
                              hipStream_t stream) {
  const float* x  = (const float*)d_in[0];
  const float* Wr = (const float*)d_in[1];
  const float* Wg = (const float*)d_in[2];
  const float* Wu = (const float*)d_in[3];
  const float* Wd = (const float*)d_in[4];
  float* out = (float*)d_out;

  char* ws = (char*)d_ws;
  int*   counts  = (int*)(ws);
  int*   cursor  = (int*)(ws + 256);
  int*   offsets = (int*)(ws + 512);
  int*   n_tiles = (int*)(ws + 768);
  int*   tiles   = (int*)(ws + 1024);
  int*   ridx    = (int*)(ws + 64 * 1024);
  float* rw      = (float*)(ws + 128 * 1024);
  int*   perm    = (int*)(ws + 192 * 1024);
  bf16*  xb      = (bf16*)(ws + (1ull << 20));
  bf16*  WgT     = (bf16*)(ws + (16ull << 20));
  bf16*  WuT     = (bf16*)(ws + (66ull << 20));
  bf16*  WdT     = (bf16*)(ws + (116ull << 20));
  bf16*  hidden  = (bf16*)(ws + (166ull << 20));
  float* pair_out = (float*)(ws + (212ull << 20));

  hipMemsetAsync(counts, 0, 64, stream);
  k_xcast<<<dim3(T_TOK * H_DIM / 2048), dim3(256), 0, stream>>>(x, xb);
  k_transpose<<<dim3(I_DIM / 64, H_DIM / 64, E_NUM), dim3(256), 0, stream>>>(Wg, WgT, H_DIM, I_DIM);
  k_transpose<<<dim3(I_DIM / 64, H_DIM / 64, E_NUM), dim3(256), 0, stream>>>(Wu, WuT, H_DIM, I_DIM);
  k_transpose<<<dim3(H_DIM / 64, I_DIM / 64, E_NUM), dim3(256), 0, stream>>>(Wd, WdT, I_DIM, H_DIM);
  k_router<<<dim3(T_TOK / 4), dim3(256), 0, stream>>>(x, Wr, ridx, rw, counts);
  k_scan<<<dim3(1), dim3(64), 0, stream>>>(counts, offsets, cursor, tiles, n_tiles);
  k_scatter<<<dim3((T_TOK + 255) / 256), dim3(256), 0, stream>>>(ridx, offsets, cursor, perm);
  k_gateup<<<dim3(I_DIM / BN, MAXTILE), dim3(256), 0, stream>>>(
      xb, WgT, WuT, perm, offsets, tiles, n_tiles, hidden);
  k_down<<<dim3(H_DIM / BN, MAXTILE), dim3(256), 0, stream>>>(
      hidden, WdT, perm, offsets, tiles, n_tiles, pair_out);
  k_combine<<<dim3(T_TOK), dim3(256), 0, stream>>>(pair_out, rw, out);
}